// Round 1
// baseline (373.064 us; speedup 1.0000x reference)
//
#include <hip/hip_runtime.h>
#include <math.h>

#define DIM 512
#define NTHR 512
#define MAXIT 72

// Block-level sum reduction over 512 threads (8 waves of 64).
__device__ __forceinline__ float block_reduce_sum(float v, float* red) {
    #pragma unroll
    for (int off = 32; off > 0; off >>= 1)
        v += __shfl_down(v, off, 64);
    const int wid  = threadIdx.x >> 6;
    const int lane = threadIdx.x & 63;
    __syncthreads();                 // protect red[] from previous use
    if (lane == 0) red[wid] = v;
    __syncthreads();
    float s = 0.0f;
    #pragma unroll
    for (int i = 0; i < 8; ++i) s += red[i];   // broadcast reads, conflict-free
    return s;
}

// One block per batch item: CG solve of (a^2*C + s^2*I) y = x - a*mean0, out = -y.
__global__ __launch_bounds__(NTHR, 1)
void vps_cg_kernel(const float* __restrict__ t_arr,
                   const float* __restrict__ x_arr,
                   const float* __restrict__ mean0,
                   const float* __restrict__ cov0,
                   float* __restrict__ out)
{
    const int b   = blockIdx.x;
    const int tid = threadIdx.x;
    const int g   = tid >> 7;     // k-parity group 0..3
    const int jq  = tid & 127;    // column-quad index (owns cols 4*jq..4*jq+3 partials)

    __shared__ float  p_s[DIM];
    __shared__ float4 part[NTHR];     // 8 KB matvec partials
    __shared__ float4 w4_s[DIM / 4];  // assembled C*p
    __shared__ float  red[8];

    // Per-batch scalars: ib = 0.1 t + 0.5*(20-0.1) t^2
    const float t  = t_arr[b];
    const float ib = 0.1f * t + 9.95f * t * t;
    const float a  = expf(-0.5f * ib);
    const float a2 = a * a;
    const float s2 = fmaxf(1.0f - a2, 1e-12f);

    // rhs, CG state: thread owns component j = tid
    const float rhs = x_arr[b * DIM + tid] - a * mean0[tid];
    float xj = 0.0f;
    float rj = rhs;
    float pj = rhs;
    p_s[tid] = pj;

    float rs = block_reduce_sum(rj * rj, red);   // contains syncs; publishes p_s too
    const float tol = rs * 1e-12f;

    const float4* __restrict__ Cq = reinterpret_cast<const float4*>(cov0);

    for (int it = 0; it < MAXIT; ++it) {
        // ---- w = a2 * (C p) + s2 * p  (symmetric form: accumulate rows scaled by p[k])
        float4 acc = make_float4(0.f, 0.f, 0.f, 0.f);
        int idx = g * (DIM / 4) + jq;        // quad index of row g, quad jq
        #pragma unroll 8
        for (int k = g; k < DIM; k += 4) {
            const float4 cv = Cq[idx];       // coalesced: 128 consecutive float4 per row
            const float  pk = p_s[k];        // wave-uniform broadcast
            acc.x = fmaf(pk, cv.x, acc.x);
            acc.y = fmaf(pk, cv.y, acc.y);
            acc.z = fmaf(pk, cv.z, acc.z);
            acc.w = fmaf(pk, cv.w, acc.w);
            idx += DIM;                      // skip 4 rows of quads
        }
        part[tid] = acc;
        __syncthreads();
        if (tid < 128) {
            const float4 a0 = part[tid];
            const float4 a1 = part[tid + 128];
            const float4 b2 = part[tid + 256];
            const float4 a3 = part[tid + 384];
            float4 s4;
            s4.x = (a0.x + a1.x) + (b2.x + a3.x);
            s4.y = (a0.y + a1.y) + (b2.y + a3.y);
            s4.z = (a0.z + a1.z) + (b2.z + a3.z);
            s4.w = (a0.w + a1.w) + (b2.w + a3.w);
            w4_s[tid] = s4;
        }
        __syncthreads();
        const float cw = reinterpret_cast<const float*>(w4_s)[tid];
        const float wj = a2 * cw + s2 * pj;

        // ---- alpha = rs / (p.w); update x, r
        const float pw    = block_reduce_sum(pj * wj, red);
        const float alpha = rs / fmaxf(pw, 1e-37f);
        xj = fmaf(alpha, pj, xj);
        rj = fmaf(-alpha, wj, rj);

        // ---- rs_new, beta, p update
        const float rsn = block_reduce_sum(rj * rj, red);
        if (rsn < tol) break;                 // uniform across block
        const float beta = rsn / fmaxf(rs, 1e-37f);
        pj = fmaf(beta, pj, rj);
        rs = rsn;
        p_s[tid] = pj;                        // prev matvec reads done (reduce synced)
        __syncthreads();
    }

    out[b * DIM + tid] = -xj;
}

extern "C" void kernel_launch(void* const* d_in, const int* in_sizes, int n_in,
                              void* d_out, int out_size, void* d_ws, size_t ws_size,
                              hipStream_t stream) {
    const float* t_arr = (const float*)d_in[0];
    const float* x_arr = (const float*)d_in[1];
    const float* m0    = (const float*)d_in[2];
    const float* c0    = (const float*)d_in[3];
    float* out = (float*)d_out;
    const int B = in_sizes[0];   // 128
    hipLaunchKernelGGL(vps_cg_kernel, dim3(B), dim3(NTHR), 0, stream,
                       t_arr, x_arr, m0, c0, out);
}

// Round 2
// 336.190 us; speedup vs baseline: 1.1097x; 1.1097x over previous
//
#include <hip/hip_runtime.h>
#include <hip/hip_fp16.h>
#include <math.h>

#define DIM 512
#define NTHR 512

// ---------- block-wide double sum reduction (512 thr = 8 waves of 64) ----------
__device__ __forceinline__ void block_reduce_sum2(float va, float vb, float* red,
                                                  float* outa, float* outb) {
    #pragma unroll
    for (int off = 32; off > 0; off >>= 1) {
        va += __shfl_down(va, off, 64);
        vb += __shfl_down(vb, off, 64);
    }
    const int wid  = threadIdx.x >> 6;
    const int lane = threadIdx.x & 63;
    __syncthreads();                       // red[] free from previous use
    if (lane == 0) { red[wid] = va; red[8 + wid] = vb; }
    __syncthreads();
    float sa = 0.f, sb = 0.f;
    #pragma unroll
    for (int i = 0; i < 8; ++i) { sa += red[i]; sb += red[8 + i]; }
    *outa = sa; *outb = sb;
}

// ---------- shared partial-assembly: acc(g,jq) -> w[tid] ----------
__device__ __forceinline__ float matvec_assemble(float4 acc, float4* part, float4* w4_s) {
    const int tid = threadIdx.x;
    __syncthreads();                       // part[] free (prev consumers done)
    part[tid] = acc;
    __syncthreads();
    if (tid < 128) {
        const float4 a0 = part[tid];
        const float4 a1 = part[tid + 128];
        const float4 a2 = part[tid + 256];
        const float4 a3 = part[tid + 384];
        float4 s4;
        s4.x = (a0.x + a1.x) + (a2.x + a3.x);
        s4.y = (a0.y + a1.y) + (a2.y + a3.y);
        s4.z = (a0.z + a1.z) + (a2.z + a3.z);
        s4.w = (a0.w + a1.w) + (a2.w + a3.w);
        w4_s[tid] = s4;
    }
    __syncthreads();
    return reinterpret_cast<const float*>(w4_s)[tid];
}

// w = C16 * p  (p fp32 in LDS, C fp16 rows; fp32 accumulate). p_s must be synced.
__device__ __forceinline__ float matvec16(const uint2* __restrict__ Cq16, const float* p_s,
                                          float4* part, float4* w4_s) {
    const int tid = threadIdx.x;
    const int g   = tid >> 7;     // row-parity group 0..3
    const int jq  = tid & 127;    // owns cols 4*jq..4*jq+3
    float4 acc = make_float4(0.f, 0.f, 0.f, 0.f);
    int idx = g * 128 + jq;       // uint2 units; row = 128 uint2
    #pragma unroll 16
    for (int k = g; k < DIM; k += 4) {
        const uint2 cv = Cq16[idx];              // 8B = 4 halfs, coalesced 1KB/row/wave-group
        const float pk = p_s[k];                 // wave-uniform LDS broadcast
        const float2 f0 = __half22float2(*reinterpret_cast<const __half2*>(&cv.x));
        const float2 f1 = __half22float2(*reinterpret_cast<const __half2*>(&cv.y));
        acc.x = fmaf(pk, f0.x, acc.x);
        acc.y = fmaf(pk, f0.y, acc.y);
        acc.z = fmaf(pk, f1.x, acc.z);
        acc.w = fmaf(pk, f1.y, acc.w);
        idx += 512;                              // 4 rows of 128 uint2
    }
    return matvec_assemble(acc, part, w4_s);
}

// w = C32 * p (fp32 path, for the refinement residual)
__device__ __forceinline__ float matvec32(const float4* __restrict__ Cq, const float* p_s,
                                          float4* part, float4* w4_s) {
    const int tid = threadIdx.x;
    const int g   = tid >> 7;
    const int jq  = tid & 127;
    float4 acc = make_float4(0.f, 0.f, 0.f, 0.f);
    int idx = g * 128 + jq;                      // float4 units; row = 128 float4
    #pragma unroll 8
    for (int k = g; k < DIM; k += 4) {
        const float4 cv = Cq[idx];
        const float  pk = p_s[k];
        acc.x = fmaf(pk, cv.x, acc.x);
        acc.y = fmaf(pk, cv.y, acc.y);
        acc.z = fmaf(pk, cv.z, acc.z);
        acc.w = fmaf(pk, cv.w, acc.w);
        idx += 512;
    }
    return matvec_assemble(acc, part, w4_s);
}

// CG on (a2*C16 + s2*I) x = b. b given per-thread; returns x component.
// Merged dots (Chronopoulos): one reduction point per iteration.
__device__ __forceinline__ float cg16(float bj, float a2, float s2,
                                      const uint2* __restrict__ Cq16,
                                      float* p_s, float4* part, float4* w4_s, float* red,
                                      int maxit, float tolf) {
    const int tid = threadIdx.x;
    float xj = 0.f, rj = bj, pj = bj;
    p_s[tid] = pj;
    float rs, dum;
    block_reduce_sum2(rj * rj, 0.f, red, &rs, &dum);   // syncs also publish p_s
    if (!(rs > 0.f)) return xj;
    const float tol = tolf * rs;
    for (int it = 0; it < maxit; ++it) {
        const float cw = matvec16(Cq16, p_s, part, w4_s);
        const float wj = a2 * cw + s2 * pj;
        float pw, ww;
        block_reduce_sum2(pj * wj, wj * wj, red, &pw, &ww);
        pw = fmaxf(pw, 1e-30f);
        const float alpha = rs / pw;
        xj = fmaf( alpha, pj, xj);
        rj = fmaf(-alpha, wj, rj);
        const float q   = rs * ww / (pw * pw);
        const float rsn = rs * (q - 1.0f);     // = ||r_new||^2 via CG identities
        if (rsn < tol) break;                  // uniform (reduced value)
        const float beta = rsn / rs;
        pj = fmaf(beta, pj, rj);
        rs = rsn;
        p_s[tid] = pj;
        __syncthreads();                       // publish p for next matvec
    }
    return xj;
}

// ---------- main: one block per batch item; fp16 CG + one fp32 refinement ----------
__global__ __launch_bounds__(NTHR, 1)
void vps_cg16_kernel(const float* __restrict__ t_arr,
                     const float* __restrict__ x_arr,
                     const float* __restrict__ mean0,
                     const float* __restrict__ cov0,
                     const uint2* __restrict__ C16,
                     float* __restrict__ out)
{
    const int b   = blockIdx.x;
    const int tid = threadIdx.x;

    __shared__ float  p_s[DIM];
    __shared__ float4 part[NTHR];
    __shared__ float4 w4_s[DIM / 4];
    __shared__ float  red[16];

    const float t  = t_arr[b];
    const float ib = 0.1f * t + 9.95f * t * t;
    const float a  = expf(-0.5f * ib);
    const float a2 = a * a;
    const float s2 = fmaxf(1.0f - a2, 1e-12f);

    const float rhs = x_arr[b * DIM + tid] - a * mean0[tid];

    // Phase 1: solve on fp16 matrix to rel-resid ~5e-3
    const float x1 = cg16(rhs, a2, s2, C16, p_s, part, w4_s, red, 32, 2.5e-5f);

    // True residual with fp32 matrix: r = rhs - (a2*C*x1 + s2*x1)
    p_s[tid] = x1;
    __syncthreads();
    const float cw = matvec32(reinterpret_cast<const float4*>(cov0), p_s, part, w4_s);
    const float rtj = rhs - (a2 * cw + s2 * x1);

    // Phase 2: correction solve (kills the fp16 matrix-perturbation error)
    const float z = cg16(rtj, a2, s2, C16, p_s, part, w4_s, red, 28, 2.5e-5f);

    out[b * DIM + tid] = -(x1 + z);
}

// ---------- fp32->fp16 conversion of cov0 into workspace ----------
__global__ void conv_fp16_kernel(const float4* __restrict__ C4, uint2* __restrict__ out2) {
    const int i = blockIdx.x * blockDim.x + threadIdx.x;   // 65536 float4 quads
    const float4 v = C4[i];
    const __half2 lo = __floats2half2_rn(v.x, v.y);
    const __half2 hi = __floats2half2_rn(v.z, v.w);
    uint2 o;
    o.x = *reinterpret_cast<const unsigned int*>(&lo);
    o.y = *reinterpret_cast<const unsigned int*>(&hi);
    out2[i] = o;
}

// ---------- fallback: proven fp32 CG (used only if ws too small) ----------
__device__ __forceinline__ float block_reduce_sum(float v, float* red) {
    #pragma unroll
    for (int off = 32; off > 0; off >>= 1) v += __shfl_down(v, off, 64);
    const int wid = threadIdx.x >> 6, lane = threadIdx.x & 63;
    __syncthreads();
    if (lane == 0) red[wid] = v;
    __syncthreads();
    float s = 0.f;
    #pragma unroll
    for (int i = 0; i < 8; ++i) s += red[i];
    return s;
}

__global__ __launch_bounds__(NTHR, 1)
void vps_cg_kernel(const float* __restrict__ t_arr, const float* __restrict__ x_arr,
                   const float* __restrict__ mean0, const float* __restrict__ cov0,
                   float* __restrict__ out)
{
    const int b = blockIdx.x, tid = threadIdx.x;
    __shared__ float  p_s[DIM];
    __shared__ float4 part[NTHR];
    __shared__ float4 w4_s[DIM / 4];
    __shared__ float  red[8];
    const float t  = t_arr[b];
    const float ib = 0.1f * t + 9.95f * t * t;
    const float a  = expf(-0.5f * ib);
    const float a2 = a * a;
    const float s2 = fmaxf(1.0f - a2, 1e-12f);
    const float rhs = x_arr[b * DIM + tid] - a * mean0[tid];
    float xj = 0.f, rj = rhs, pj = rhs;
    p_s[tid] = pj;
    float rs = block_reduce_sum(rj * rj, red);
    const float tol = rs * 1e-12f;
    for (int it = 0; it < 72; ++it) {
        const float cw = matvec32(reinterpret_cast<const float4*>(cov0), p_s, part, w4_s);
        const float wj = a2 * cw + s2 * pj;
        const float pw = block_reduce_sum(pj * wj, red);
        const float alpha = rs / fmaxf(pw, 1e-37f);
        xj = fmaf(alpha, pj, xj);
        rj = fmaf(-alpha, wj, rj);
        const float rsn = block_reduce_sum(rj * rj, red);
        if (rsn < tol) break;
        const float beta = rsn / fmaxf(rs, 1e-37f);
        pj = fmaf(beta, pj, rj);
        rs = rsn;
        p_s[tid] = pj;
        __syncthreads();
    }
    out[b * DIM + tid] = -xj;
}

extern "C" void kernel_launch(void* const* d_in, const int* in_sizes, int n_in,
                              void* d_out, int out_size, void* d_ws, size_t ws_size,
                              hipStream_t stream) {
    const float* t_arr = (const float*)d_in[0];
    const float* x_arr = (const float*)d_in[1];
    const float* m0    = (const float*)d_in[2];
    const float* c0    = (const float*)d_in[3];
    float* out = (float*)d_out;
    const int B = in_sizes[0];   // 128
    const size_t need = (size_t)DIM * DIM * sizeof(unsigned short);  // 512 KB
    if (ws_size >= need) {
        hipLaunchKernelGGL(conv_fp16_kernel, dim3((DIM * DIM / 4) / 256), dim3(256), 0, stream,
                           reinterpret_cast<const float4*>(c0), (uint2*)d_ws);
        hipLaunchKernelGGL(vps_cg16_kernel, dim3(B), dim3(NTHR), 0, stream,
                           t_arr, x_arr, m0, c0, (const uint2*)d_ws, out);
    } else {
        hipLaunchKernelGGL(vps_cg_kernel, dim3(B), dim3(NTHR), 0, stream,
                           t_arr, x_arr, m0, c0, out);
    }
}

// Round 4
// 276.524 us; speedup vs baseline: 1.3491x; 1.2158x over previous
//
#include <hip/hip_runtime.h>
#include <hip/hip_fp16.h>
#include <math.h>

#define DIM   512
#define NTHR  512
#define SLABR 136        // rows of C cached in LDS (136 * 1KB = 136 KB)

// ---------- 8-wave block sum (phase init only) ----------
__device__ __forceinline__ float block_reduce_sum(float v, float* red) {
    #pragma unroll
    for (int off = 32; off > 0; off >>= 1) v += __shfl_down(v, off, 64);
    const int wid = threadIdx.x >> 6, lane = threadIdx.x & 63;
    __syncthreads();
    if (lane == 0) red[wid] = v;
    __syncthreads();
    float s = 0.f;
    #pragma unroll
    for (int i = 0; i < 8; ++i) s += red[i];
    return s;
}

// ---------- fp32 matvec (refinement residual), round-1-proven ----------
__device__ __forceinline__ float matvec_assemble(float4 acc, float4* part, float4* w4_s) {
    const int tid = threadIdx.x;
    __syncthreads();
    part[tid] = acc;
    __syncthreads();
    if (tid < 128) {
        const float4 a0 = part[tid], a1 = part[tid + 128];
        const float4 a2 = part[tid + 256], a3 = part[tid + 384];
        float4 s4;
        s4.x = (a0.x + a1.x) + (a2.x + a3.x);
        s4.y = (a0.y + a1.y) + (a2.y + a3.y);
        s4.z = (a0.z + a1.z) + (a2.z + a3.z);
        s4.w = (a0.w + a1.w) + (a2.w + a3.w);
        w4_s[tid] = s4;
    }
    __syncthreads();
    return reinterpret_cast<const float*>(w4_s)[tid];
}

__device__ __forceinline__ float matvec32(const float4* __restrict__ Cq, const float* p_s,
                                          float4* part, float4* w4_s) {
    const int tid = threadIdx.x;
    const int g = tid >> 7, jq = tid & 127;
    float4 acc = make_float4(0.f, 0.f, 0.f, 0.f);
    int idx = g * 128 + jq;
    #pragma unroll 8
    for (int k = g; k < DIM; k += 4) {
        const float4 cv = Cq[idx];
        const float  pk = p_s[k];
        acc.x = fmaf(pk, cv.x, acc.x);
        acc.y = fmaf(pk, cv.y, acc.y);
        acc.z = fmaf(pk, cv.z, acc.z);
        acc.w = fmaf(pk, cv.w, acc.w);
        idx += 512;
    }
    return matvec_assemble(acc, part, w4_s);
}

// ---------- fp16-C matvec body: LDS slab rows [0,SLABR) + L2 rows [SLABR,512) ----------
// Round-2 layout: uint2 at [k*128 + jq] = cols 4jq..4jq+3 of row k (fp16).
// fp32 p broadcast, fp32 accumulate — numerics identical to round 2.
__device__ __forceinline__ float4 matvec16_body(const uint2* __restrict__ Cg,
                                                const uint2* C_lds,
                                                const float* p_s, int g, int jq) {
    float4 acc = make_float4(0.f, 0.f, 0.f, 0.f);
    int idx = g * 128 + jq;
    #pragma unroll 4
    for (int k = g; k < SLABR; k += 4) {          // 34 steps from LDS
        const uint2 cv = C_lds[idx];
        const float pk = p_s[k];
        const float2 f0 = __half22float2(*reinterpret_cast<const __half2*>(&cv.x));
        const float2 f1 = __half22float2(*reinterpret_cast<const __half2*>(&cv.y));
        acc.x = fmaf(pk, f0.x, acc.x);
        acc.y = fmaf(pk, f0.y, acc.y);
        acc.z = fmaf(pk, f1.x, acc.z);
        acc.w = fmaf(pk, f1.y, acc.w);
        idx += 512;
    }
    idx = (SLABR + g) * 128 + jq;
    #pragma unroll 8
    for (int k = SLABR + g; k < DIM; k += 4) {    // 94 steps from L2
        const uint2 cv = Cg[idx];
        const float pk = p_s[k];
        const float2 f0 = __half22float2(*reinterpret_cast<const __half2*>(&cv.x));
        const float2 f1 = __half22float2(*reinterpret_cast<const __half2*>(&cv.y));
        acc.x = fmaf(pk, f0.x, acc.x);
        acc.y = fmaf(pk, f0.y, acc.y);
        acc.z = fmaf(pk, f1.x, acc.z);
        acc.w = fmaf(pk, f1.y, acc.w);
        idx += 512;
    }
    return acc;
}

// ---------- fused CG phase: 3 barriers/iter, Chronopoulos merged dots ----------
__device__ float cg_fused(float bj, float a2, float s2,
                          const uint2* __restrict__ Cg, const uint2* C_lds,
                          float* p_s, float* w_s, float4* part, float* red,
                          int maxit, float tolf)
{
    const int tid = threadIdx.x;
    const int g   = tid >> 7;
    const int jq  = tid & 127;

    float xj = 0.f, rj = bj, pj = bj;
    p_s[tid] = pj;
    float rs = block_reduce_sum(rj * rj, red);   // internal barriers publish p_s
    if (!(rs > 0.f)) return xj;
    const float tol = tolf * rs;

    for (int it = 0; it < maxit; ++it) {
        const float4 acc = matvec16_body(Cg, C_lds, p_s, g, jq);
        part[tid] = acc;
        __syncthreads();                                  // A
        if (tid < 128) {
            const float4 a0 = part[tid],       a1 = part[tid + 128];
            const float4 b2 = part[tid + 256], a3 = part[tid + 384];
            float4 cw;
            cw.x = (a0.x + a1.x) + (b2.x + a3.x);
            cw.y = (a0.y + a1.y) + (b2.y + a3.y);
            cw.z = (a0.z + a1.z) + (b2.z + a3.z);
            cw.w = (a0.w + a1.w) + (b2.w + a3.w);
            const float4 p4 = reinterpret_cast<const float4*>(p_s)[tid];
            float4 w4;
            w4.x = fmaf(a2, cw.x, s2 * p4.x);
            w4.y = fmaf(a2, cw.y, s2 * p4.y);
            w4.z = fmaf(a2, cw.z, s2 * p4.z);
            w4.w = fmaf(a2, cw.w, s2 * p4.w);
            reinterpret_cast<float4*>(w_s)[tid] = w4;
            float pwp = p4.x*w4.x + p4.y*w4.y + p4.z*w4.z + p4.w*w4.w;
            float wwp = w4.x*w4.x + w4.y*w4.y + w4.z*w4.z + w4.w*w4.w;
            #pragma unroll
            for (int off = 32; off > 0; off >>= 1) {
                pwp += __shfl_down(pwp, off, 64);
                wwp += __shfl_down(wwp, off, 64);
            }
            if ((tid & 63) == 0) { red[(tid >> 6) * 2] = pwp; red[(tid >> 6) * 2 + 1] = wwp; }
        }
        __syncthreads();                                  // B
        const float pw = fmaxf(red[0] + red[2], 1e-30f);
        const float ww = red[1] + red[3];
        const float alpha = rs / pw;
        const float wj = w_s[tid];
        xj = fmaf( alpha, pj, xj);
        rj = fmaf(-alpha, wj, rj);
        const float q   = rs * ww / (pw * pw);
        const float rsn = rs * (q - 1.0f);                // ||r_new||^2 via CG identities
        if (!(rsn > tol)) break;                          // uniform; NaN/neg safe
        const float beta = rsn / rs;
        pj = fmaf(beta, pj, rj);
        rs = rsn;
        p_s[tid] = pj;
        __syncthreads();                                  // C
    }
    return xj;
}

// ---------- main solver: one block per item ----------
__global__ __launch_bounds__(NTHR, 1)
void vps_solve_kernel(const float* __restrict__ t_arr,
                      const float* __restrict__ x_arr,
                      const float* __restrict__ mean0,
                      const float* __restrict__ cov0,
                      const uint2* __restrict__ C16,
                      float* __restrict__ out)
{
    __shared__ uint2  C_lds[SLABR * 128];        // 136 KB slab (rows 0..135)
    __shared__ float4 part[NTHR];                // 8 KB
    __shared__ float4 p4_s[DIM / 4];             // 2 KB
    __shared__ float4 w4_s[DIM / 4];             // 2 KB
    __shared__ float  red[16];
    float* p_s = (float*)p4_s;
    float* w_s = (float*)w4_s;

    const int b   = blockIdx.x;
    const int tid = threadIdx.x;

    const float t  = t_arr[b];
    const float ib = 0.1f * t + 9.95f * t * t;
    const float a  = expf(-0.5f * ib);
    const float a2 = a * a;
    const float s2 = fmaxf(1.0f - a2, 1e-12f);

    const float rhs = x_arr[b * DIM + tid] - a * mean0[tid];

    // load slab once, vectorized (17 uint4 per thread, coalesced)
    {
        const uint4* src = reinterpret_cast<const uint4*>(C16);
        uint4* dst = reinterpret_cast<uint4*>(C_lds);
        for (int i = tid; i < SLABR * 128 / 2; i += NTHR) dst[i] = src[i];
    }
    __syncthreads();

    // Phase 1: CG on fp16 matrix (fp32 p, fp32 accumulate)
    const float x1 = cg_fused(rhs, a2, s2, C16, C_lds, p_s, w_s, part, red, 24, 1e-4f);

    // Exact fp32 residual
    p_s[tid] = x1;
    __syncthreads();
    const float cw  = matvec32(reinterpret_cast<const float4*>(cov0), p_s, part, w4_s);
    const float rtj = rhs - (a2 * cw + s2 * x1);

    // Phase 2: correction solve (absorbs fp16 matrix perturbation)
    const float z = cg_fused(rtj, a2, s2, C16, C_lds, p_s, w_s, part, red, 24, 1e-4f);

    out[b * DIM + tid] = -(x1 + z);
}

// ---------- fp32->fp16 conversion (round-2 proven, row-major layout) ----------
__global__ void conv_fp16_kernel(const float4* __restrict__ C4, uint2* __restrict__ out2) {
    const int i = blockIdx.x * blockDim.x + threadIdx.x;   // 65536 float4 quads
    const float4 v = C4[i];
    const __half2 lo = __floats2half2_rn(v.x, v.y);
    const __half2 hi = __floats2half2_rn(v.z, v.w);
    uint2 o;
    o.x = *reinterpret_cast<const unsigned int*>(&lo);
    o.y = *reinterpret_cast<const unsigned int*>(&hi);
    out2[i] = o;
}

// ---------- fallback: proven fp32 CG (only if ws too small) ----------
__global__ __launch_bounds__(NTHR, 1)
void vps_cg_kernel(const float* __restrict__ t_arr, const float* __restrict__ x_arr,
                   const float* __restrict__ mean0, const float* __restrict__ cov0,
                   float* __restrict__ out)
{
    const int b = blockIdx.x, tid = threadIdx.x;
    __shared__ float4 part[NTHR];
    __shared__ float4 p4_s[DIM / 4];
    __shared__ float4 w4_s[DIM / 4];
    __shared__ float  red[16];
    float* p_s = (float*)p4_s;
    const float t  = t_arr[b];
    const float ib = 0.1f * t + 9.95f * t * t;
    const float a  = expf(-0.5f * ib);
    const float a2 = a * a;
    const float s2 = fmaxf(1.0f - a2, 1e-12f);
    const float rhs = x_arr[b * DIM + tid] - a * mean0[tid];
    float xj = 0.f, rj = rhs, pj = rhs;
    p_s[tid] = pj;
    float rs = block_reduce_sum(rj * rj, red);
    const float tol = rs * 1e-12f;
    for (int it = 0; it < 72; ++it) {
        const float cw = matvec32(reinterpret_cast<const float4*>(cov0), p_s, part, w4_s);
        const float wj = a2 * cw + s2 * pj;
        const float pw = block_reduce_sum(pj * wj, red);
        const float alpha = rs / fmaxf(pw, 1e-37f);
        xj = fmaf(alpha, pj, xj);
        rj = fmaf(-alpha, wj, rj);
        const float rsn = block_reduce_sum(rj * rj, red);
        if (rsn < tol) break;
        const float beta = rsn / fmaxf(rs, 1e-37f);
        pj = fmaf(beta, pj, rj);
        rs = rsn;
        p_s[tid] = pj;
        __syncthreads();
    }
    out[b * DIM + tid] = -xj;
}

extern "C" void kernel_launch(void* const* d_in, const int* in_sizes, int n_in,
                              void* d_out, int out_size, void* d_ws, size_t ws_size,
                              hipStream_t stream) {
    const float* t_arr = (const float*)d_in[0];
    const float* x_arr = (const float*)d_in[1];
    const float* m0    = (const float*)d_in[2];
    const float* c0    = (const float*)d_in[3];
    float* out = (float*)d_out;
    const int B = in_sizes[0];   // 128
    const size_t need = (size_t)DIM * DIM * sizeof(unsigned short);  // 512 KB fp16
    if (ws_size >= need) {
        hipLaunchKernelGGL(conv_fp16_kernel, dim3((DIM * DIM / 4) / 256), dim3(256), 0, stream,
                           reinterpret_cast<const float4*>(c0), (uint2*)d_ws);
        hipLaunchKernelGGL(vps_solve_kernel, dim3(B), dim3(NTHR), 0, stream,
                           t_arr, x_arr, m0, c0, (const uint2*)d_ws, out);
    } else {
        hipLaunchKernelGGL(vps_cg_kernel, dim3(B), dim3(NTHR), 0, stream,
                           t_arr, x_arr, m0, c0, out);
    }
}